// Round 2
// baseline (845.713 us; speedup 1.0000x reference)
//
#include <hip/hip_runtime.h>
#include <hip/hip_bf16.h>

#define NTOK 8192   // B*S
#define DDIM 1024
#define NEXP 32
#define HDIM 128
#define TOPK 4
#define TILE 64

// ---------------- Kernel 1: gating logits + top-4 + scatter ----------------
__global__ __launch_bounds__(256) void gate_topk_kernel(
    const float* __restrict__ x,         // [N,D]
    const float* __restrict__ es,        // [E,D]
    int* __restrict__ cnt,               // [E]
    int* __restrict__ tok_list,          // [E][N] packed (n*4 + slot)
    float* __restrict__ gates)           // [N*4] gate per (token, slot)
{
    const int n    = blockIdx.x;
    const int tid  = threadIdx.x;
    const int wave = tid >> 6;
    const int lane = tid & 63;

    __shared__ float xs[DDIM];
    __shared__ float glog[NEXP];

    // stage x row (4 KB)
    const float4* xrow = (const float4*)(x + (size_t)n * DDIM);
    for (int i = tid; i < DDIM / 4; i += 256) {
        float4 v = xrow[i];
        xs[i * 4 + 0] = v.x; xs[i * 4 + 1] = v.y;
        xs[i * 4 + 2] = v.z; xs[i * 4 + 3] = v.w;
    }
    __syncthreads();

    // each of 4 waves handles 8 experts
    for (int k = 0; k < 8; ++k) {
        int e = wave + 4 * k;
        const float* er = es + (size_t)e * DDIM;
        float acc = 0.f;
        #pragma unroll 4
        for (int d = lane; d < DDIM; d += 64)
            acc = fmaf(xs[d], er[d], acc);
        #pragma unroll
        for (int off = 32; off > 0; off >>= 1)
            acc += __shfl_down(acc, off, 64);
        if (lane == 0) glog[e] = acc;
    }
    __syncthreads();

    if (tid == 0) {
        float lg[NEXP];
        #pragma unroll
        for (int e = 0; e < NEXP; ++e) lg[e] = glog[e];
        #pragma unroll
        for (int j = 0; j < TOPK; ++j) {
            int bi = 0; float bv = lg[0];
            for (int e = 1; e < NEXP; ++e) {
                if (lg[e] > bv) { bv = lg[e]; bi = e; }  // strict > : lowest index wins ties
            }
            lg[bi] = -3.0e38f;
            float g = 1.f / (1.f + expf(-bv));           // sigmoid gate weight
            gates[n * TOPK + j] = g;
            int pos = atomicAdd(&cnt[bi], 1);
            tok_list[(size_t)bi * NTOK + pos] = n * TOPK + j;  // packed token*4+slot
        }
    }
}

// ---------------- Kernel 2: grouped expert FFN ----------------
// block = (expert e, tile of up to 64 of its tokens), 256 threads
__global__ __launch_bounds__(256) void expert_ffn_kernel(
    const float* __restrict__ x,        // [N,D]
    const float* __restrict__ keys,     // [E,D,H]
    const float* __restrict__ values,   // [E,H,D]
    const int* __restrict__ cnt,
    const int* __restrict__ tok_list,   // [E][N] packed
    const float* __restrict__ gates,    // [N*4]
    float* __restrict__ out)            // [N,D] (pre-zeroed)
{
    const int e    = blockIdx.y;
    const int tile = blockIdx.x;
    const int c    = cnt[e];
    const int base = tile * TILE;
    if (base >= c) return;
    const int nt  = min(TILE, c - base);
    const int tid = threadIdx.x;

    // LDS: Xs 8448B + KV 16384B + Hs 33792B + toks/gs 512B = ~58.6 KB
    __shared__ __align__(16) float Xs[TILE][33];     // 64x32 chunk of X, pad 33
    __shared__ __align__(16) float KV[4096];         // ph1: K[32][128]; ph2: V[128][32]
    __shared__ __align__(16) float Hs[TILE][132];    // H tile (relu*gate), pad 132
    __shared__ int   toks[TILE];
    __shared__ float gs[TILE];

    if (tid < TILE) {
        if (tid < nt) {
            int v = tok_list[(size_t)e * NTOK + base + tid];
            toks[tid] = v >> 2;          // token index
            gs[tid]   = gates[v];        // gate weight for (token, slot)
        } else {
            toks[tid] = -1;
            gs[tid]   = 0.f;
        }
    }
    __syncthreads();

    const int tg = tid >> 4;    // 0..15 : token group, t = 4*tg+ti
    const int hg = tid & 15;    // 0..15 : h group,    h = 8*hg+hi  (phase 1)
    const int dg = tid & 15;    // 0..15 : d group,    d = 2*dg+di  (phase 2)

    // ---------- phase 1: Hacc[64][128] = X_tile @ K_e ----------
    float acc[4][8];
    #pragma unroll
    for (int i = 0; i < 4; ++i)
        #pragma unroll
        for (int j = 0; j < 8; ++j) acc[i][j] = 0.f;

    const float* Ke = keys + (size_t)e * DDIM * HDIM;

    for (int dc = 0; dc < DDIM; dc += 32) {
        // load Xs[64][32] : 512 float4, 2/thread (rows gathered by token)
        #pragma unroll
        for (int k = 0; k < 2; ++k) {
            int q  = tid + k * 256;
            int r  = q >> 3;          // 8 float4 per row
            int c4 = q & 7;
            int tok = toks[r];
            float4 v = make_float4(0.f, 0.f, 0.f, 0.f);
            if (tok >= 0)
                v = *(const float4*)(x + (size_t)tok * DDIM + dc + c4 * 4);
            Xs[r][c4 * 4 + 0] = v.x; Xs[r][c4 * 4 + 1] = v.y;
            Xs[r][c4 * 4 + 2] = v.z; Xs[r][c4 * 4 + 3] = v.w;
        }
        // load K chunk [32][128] : 1024 float4, 4/thread
        #pragma unroll
        for (int k = 0; k < 4; ++k) {
            int q  = tid + k * 256;
            int r  = q >> 5;          // 32 float4 per row
            int c4 = q & 31;
            *(float4*)&KV[r * HDIM + c4 * 4] =
                *(const float4*)(Ke + (size_t)(dc + r) * HDIM + c4 * 4);
        }
        __syncthreads();

        #pragma unroll 4
        for (int dk = 0; dk < 32; ++dk) {
            float xv[4], kv[8];
            #pragma unroll
            for (int ti = 0; ti < 4; ++ti) xv[ti] = Xs[4 * tg + ti][dk];
            float4 a = *(const float4*)&KV[dk * HDIM + 8 * hg];
            float4 b = *(const float4*)&KV[dk * HDIM + 8 * hg + 4];
            kv[0] = a.x; kv[1] = a.y; kv[2] = a.z; kv[3] = a.w;
            kv[4] = b.x; kv[5] = b.y; kv[6] = b.z; kv[7] = b.w;
            #pragma unroll
            for (int ti = 0; ti < 4; ++ti)
                #pragma unroll
                for (int hi = 0; hi < 8; ++hi)
                    acc[ti][hi] = fmaf(xv[ti], kv[hi], acc[ti][hi]);
        }
        __syncthreads();
    }

    // relu * gate, write Hs
    #pragma unroll
    for (int ti = 0; ti < 4; ++ti) {
        int t = 4 * tg + ti;
        float g = gs[t];
        #pragma unroll
        for (int hi = 0; hi < 8; ++hi)
            Hs[t][8 * hg + hi] = fmaxf(acc[ti][hi], 0.f) * g;
    }

    // ---------- phase 2: out_tile += Hs @ V_e ----------
    const float* Ve = values + (size_t)e * HDIM * DDIM;

    for (int dc2 = 0; dc2 < DDIM; dc2 += 32) {
        __syncthreads();  // KV reusable; also makes Hs visible on first iter
        // load V chunk [128][32] : 1024 float4, 4/thread
        #pragma unroll
        for (int k = 0; k < 4; ++k) {
            int q  = tid + k * 256;
            int r  = q >> 3;          // 8 float4 per row of 32
            int c4 = q & 7;
            *(float4*)&KV[r * 32 + c4 * 4] =
                *(const float4*)(Ve + (size_t)r * DDIM + dc2 + c4 * 4);
        }
        __syncthreads();

        float acc2[4][2];
        #pragma unroll
        for (int i = 0; i < 4; ++i) { acc2[i][0] = 0.f; acc2[i][1] = 0.f; }

        #pragma unroll 4
        for (int h = 0; h < HDIM; ++h) {
            float2 vv = *(const float2*)&KV[h * 32 + 2 * dg];
            #pragma unroll
            for (int ti = 0; ti < 4; ++ti) {
                float hv = Hs[4 * tg + ti][h];
                acc2[ti][0] = fmaf(hv, vv.x, acc2[ti][0]);
                acc2[ti][1] = fmaf(hv, vv.y, acc2[ti][1]);
            }
        }

        // accumulate into out (token appears in up to 4 expert lists -> atomic)
        #pragma unroll
        for (int ti = 0; ti < 4; ++ti) {
            int t = 4 * tg + ti;
            if (t < nt) {
                float* op = out + (size_t)toks[t] * DDIM + dc2 + 2 * dg;
                atomicAdd(&op[0], acc2[ti][0]);
                atomicAdd(&op[1], acc2[ti][1]);
            }
        }
    }
}

extern "C" void kernel_launch(void* const* d_in, const int* in_sizes, int n_in,
                              void* d_out, int out_size, void* d_ws, size_t ws_size,
                              hipStream_t stream) {
    const float* x      = (const float*)d_in[0];
    const float* es     = (const float*)d_in[1];
    const float* keys   = (const float*)d_in[2];
    const float* values = (const float*)d_in[3];
    float* out          = (float*)d_out;

    // workspace layout (~1.18 MB)
    int*   cnt      = (int*)d_ws;                                         // 32 ints
    int*   tok_list = (int*)((char*)d_ws + 256);                          // [E][N] ints, 1 MB
    float* gates    = (float*)((char*)d_ws + 256 +
                               (size_t)NEXP * NTOK * sizeof(int));        // [N*4] floats, 128 KB

    hipMemsetAsync(cnt, 0, NEXP * sizeof(int), stream);
    hipMemsetAsync(out, 0, (size_t)out_size * sizeof(float), stream);

    gate_topk_kernel<<<NTOK, 256, 0, stream>>>(x, es, cnt, tok_list, gates);

    dim3 grid(NTOK / TILE, NEXP);
    expert_ffn_kernel<<<grid, 256, 0, stream>>>(x, keys, values, cnt, tok_list,
                                                gates, out);
}

// Round 3
// 357.067 us; speedup vs baseline: 2.3685x; 2.3685x over previous
//
#include <hip/hip_runtime.h>
#include <hip/hip_bf16.h>

#define NTOK 8192   // B*S
#define DDIM 1024
#define NEXP 32
#define HDIM 128
#define TOPK 4
#define TILE 64

#define XS_STRIDE 40    // bf16 elements per Xs row (32 + 8 pad) -> balanced banks
#define HS_STRIDE 136   // bf16 elements per Hs row (128 + 8 pad) -> balanced banks

typedef __attribute__((ext_vector_type(8))) short bf16x8;
typedef __attribute__((ext_vector_type(4))) float f32x4;

__device__ inline unsigned short f2bf(float f) {
    unsigned int u = __builtin_bit_cast(unsigned int, f);
    unsigned int r = (u + 0x7fffu + ((u >> 16) & 1u)) >> 16;   // RNE
    return (unsigned short)r;
}

// ---------------- Kernel P: convert K/V to bf16 in MFMA-B layout ----------------
// Kb[e][k>>3][n][k&7] for keys [E][D=1024 k][H=128 n]
// Vb[e][k>>3][n][k&7] for values [E][H=128 k][D=1024 n]
__global__ __launch_bounds__(256) void prep_weights(
    const float* __restrict__ keys, const float* __restrict__ values,
    unsigned short* __restrict__ Kb, unsigned short* __restrict__ Vb)
{
    int idx = blockIdx.x * 256 + threadIdx.x;
    unsigned short o[8];
    if (idx < NEXP * 128 * 128) {            // keys: (e, k0=k>>3 [128], n [128])
        int n = idx & 127, k0 = (idx >> 7) & 127, e = idx >> 14;
        const float* s = keys + ((size_t)e * DDIM + k0 * 8) * HDIM + n;
        #pragma unroll
        for (int j = 0; j < 8; ++j) o[j] = f2bf(s[(size_t)j * HDIM]);
        *(uint4*)&Kb[(size_t)idx * 8] = *(uint4*)o;
    } else {
        idx -= NEXP * 128 * 128;             // values: (e, k0 [16], n [1024])
        int n = idx & 1023, k0 = (idx >> 10) & 15, e = idx >> 14;
        const float* s = values + ((size_t)e * HDIM + k0 * 8) * DDIM + n;
        #pragma unroll
        for (int j = 0; j < 8; ++j) o[j] = f2bf(s[(size_t)j * DDIM]);
        *(uint4*)&Vb[(size_t)idx * 8] = *(uint4*)o;
    }
}

// ---------------- Kernel 1: gating logits (fp32) + top-4 + scatter ----------------
// 64 tokens per block, es tile staged in LDS (x64 reuse)
__global__ __launch_bounds__(256) void gate_topk2(
    const float* __restrict__ x, const float* __restrict__ es,
    int* __restrict__ cnt, int* __restrict__ tok_list, float* __restrict__ gates)
{
    const int n0  = blockIdx.x * 64;
    const int tid = threadIdx.x;

    __shared__ float Xt[64 * 65];   // [d][t] transposed, stride 65
    __shared__ float Es[32 * 68];   // [e][d], stride 68 (float4-friendly)
    __shared__ float Ls[64 * 33];   // logits [t][e]

    const int t4 = (tid & 15) * 4;  // this thread's 4 tokens
    const int eg = tid >> 4;        // this thread's expert pair: 2*eg, 2*eg+1
    const int r  = tid >> 2, cq = tid & 3;   // X staging
    const int er = tid >> 3, c8 = tid & 7;   // es staging

    float acc[4][2] = {};

    for (int dc = 0; dc < DDIM; dc += 64) {
        __syncthreads();
        #pragma unroll
        for (int i = 0; i < 4; ++i) {
            float4 v = *(const float4*)&x[(size_t)(n0 + r) * DDIM + dc + cq * 16 + i * 4];
            int d0 = cq * 16 + i * 4;
            Xt[(d0 + 0) * 65 + r] = v.x; Xt[(d0 + 1) * 65 + r] = v.y;
            Xt[(d0 + 2) * 65 + r] = v.z; Xt[(d0 + 3) * 65 + r] = v.w;
        }
        #pragma unroll
        for (int i = 0; i < 2; ++i)
            *(float4*)&Es[er * 68 + c8 * 8 + i * 4] =
                *(const float4*)&es[(size_t)er * DDIM + dc + c8 * 8 + i * 4];
        __syncthreads();

        #pragma unroll 4
        for (int d = 0; d < 64; d += 2) {
            float2 e0 = *(const float2*)&Es[(eg * 2 + 0) * 68 + d];
            float2 e1 = *(const float2*)&Es[(eg * 2 + 1) * 68 + d];
            #pragma unroll
            for (int i = 0; i < 4; ++i) {
                float a0 = Xt[d * 65 + t4 + i];
                float a1 = Xt[(d + 1) * 65 + t4 + i];
                acc[i][0] = fmaf(a0, e0.x, fmaf(a1, e0.y, acc[i][0]));
                acc[i][1] = fmaf(a0, e1.x, fmaf(a1, e1.y, acc[i][1]));
            }
        }
    }

    #pragma unroll
    for (int i = 0; i < 4; ++i) {
        Ls[(t4 + i) * 33 + eg * 2 + 0] = acc[i][0];
        Ls[(t4 + i) * 33 + eg * 2 + 1] = acc[i][1];
    }
    __syncthreads();

    if (tid < 64) {
        int n = n0 + tid;
        float lg[NEXP];
        #pragma unroll
        for (int e = 0; e < NEXP; ++e) lg[e] = Ls[tid * 33 + e];
        #pragma unroll
        for (int j = 0; j < TOPK; ++j) {
            int bi = 0; float bv = lg[0];
            for (int e = 1; e < NEXP; ++e)
                if (lg[e] > bv) { bv = lg[e]; bi = e; }   // strict >: lowest index on ties
            lg[bi] = -3.0e38f;
            gates[n * TOPK + j] = 1.f / (1.f + expf(-bv));
            int pos = atomicAdd(&cnt[bi], 1);
            tok_list[(size_t)bi * NTOK + pos] = n * TOPK + j;
        }
    }
}

// ---------------- Kernel 2: grouped expert FFN via bf16 MFMA ----------------
// block = (expert, 64-token tile), 4 waves; wave quadrant 32 rows x 64 cols
__global__ __launch_bounds__(256, 3) void expert_ffn_mfma(
    const float* __restrict__ x,
    const unsigned short* __restrict__ Kb,   // [E][128][128][8]
    const unsigned short* __restrict__ Vb,   // [E][16][1024][8]
    const int* __restrict__ cnt,
    const int* __restrict__ tok_list,
    const float* __restrict__ gates,
    float* __restrict__ out)                 // [N,D] pre-zeroed
{
    const int e    = blockIdx.y;
    const int tile = blockIdx.x;
    const int c    = cnt[e];
    const int base = tile * TILE;
    if (base >= c) return;
    const int nt  = min(TILE, c - base);
    const int tid  = threadIdx.x;
    const int wave = tid >> 6, lane = tid & 63;
    const int lm   = lane & 15, quad = lane >> 4;
    const int r2   = (wave >> 1) * 32;   // row quadrant base
    const int c2   = (wave & 1) * 64;    // col quadrant base

    __shared__ __align__(16) unsigned short Hs[64 * HS_STRIDE];  // 17408 B
    __shared__ __align__(16) unsigned short SB[16384];           // 32768 B (Xs+Ks | Vs)
    __shared__ int   toks[TILE];
    __shared__ float gs[TILE];

    if (tid < TILE) {
        if (tid < nt) {
            int v = tok_list[(size_t)e * NTOK + base + tid];
            toks[tid] = v >> 2;
            gs[tid]   = gates[v];
        } else { toks[tid] = -1; gs[tid] = 0.f; }
    }
    __syncthreads();

    unsigned short* Xs = SB;            // [64][XS_STRIDE]
    unsigned short* Ks = SB + 64 * XS_STRIDE;  // 4096 elements
    const unsigned short* Ke = Kb + (size_t)e * (128 * 128 * 8);

    f32x4 acc[2][4];
    #pragma unroll
    for (int i = 0; i < 2; ++i)
        #pragma unroll
        for (int j = 0; j < 4; ++j) acc[i][j] = (f32x4){0.f, 0.f, 0.f, 0.f};

    // ---------- phase 1: C1[64][128] = Xtile @ K_e ----------
    for (int dc = 0; dc < DDIM; dc += 32) {
        {   // stage Xs: fp32 -> bf16, rows gathered by token
            int xr = tid >> 2, xc = (tid & 3) * 8;
            int tok = toks[xr];
            float4 v0 = make_float4(0.f,0.f,0.f,0.f), v1 = v0;
            if (tok >= 0) {
                const float* s = x + (size_t)tok * DDIM + dc + xc;
                v0 = *(const float4*)s; v1 = *(const float4*)(s + 4);
            }
            unsigned short p[8] = { f2bf(v0.x), f2bf(v0.y), f2bf(v0.z), f2bf(v0.w),
                                    f2bf(v1.x), f2bf(v1.y), f2bf(v1.z), f2bf(v1.w) };
            *(uint4*)&Xs[xr * XS_STRIDE + xc] = *(uint4*)p;
        }
        #pragma unroll
        for (int i = 0; i < 2; ++i) {   // stage Ks: contiguous 8 KB
            int u = i * 256 + tid;
            *(uint4*)&Ks[u * 8] = *(const uint4*)&Ke[(size_t)dc * 128 + u * 8];
        }
        __syncthreads();

        bf16x8 a0 = *(const bf16x8*)&Xs[(r2 + lm) * XS_STRIDE + quad * 8];
        bf16x8 a1 = *(const bf16x8*)&Xs[(r2 + 16 + lm) * XS_STRIDE + quad * 8];
        #pragma unroll
        for (int tj = 0; tj < 4; ++tj) {
            bf16x8 b = *(const bf16x8*)&Ks[(quad * 128 + c2 + tj * 16 + lm) * 8];
            acc[0][tj] = __builtin_amdgcn_mfma_f32_16x16x32_bf16(a0, b, acc[0][tj], 0, 0, 0);
            acc[1][tj] = __builtin_amdgcn_mfma_f32_16x16x32_bf16(a1, b, acc[1][tj], 0, 0, 0);
        }
        __syncthreads();
    }

    // relu * gate -> Hs (bf16, A-operand layout = row-major)
    #pragma unroll
    for (int ti = 0; ti < 2; ++ti)
        #pragma unroll
        for (int reg = 0; reg < 4; ++reg) {
            int m = r2 + ti * 16 + quad * 4 + reg;
            float g = gs[m];
            #pragma unroll
            for (int tj = 0; tj < 4; ++tj)
                Hs[m * HS_STRIDE + c2 + tj * 16 + lm] =
                    f2bf(fmaxf(acc[ti][tj][reg], 0.f) * g);
        }

    // ---------- phase 2: out_tile += Hs @ V_e ----------
    const unsigned short* Ve = Vb + (size_t)e * (16 * 1024 * 8);
    unsigned short* Vs = SB;   // [16 kg][128 n][8 j] = 32 KB

    for (int nc = 0; nc < 8; ++nc) {
        __syncthreads();   // SB reuse + Hs visibility on first iter
        #pragma unroll
        for (int i = 0; i < 8; ++i) {
            int u = i * 256 + tid;
            int kg = u >> 7, nn = u & 127;
            *(uint4*)&Vs[u * 8] = *(const uint4*)&Ve[((size_t)kg * 1024 + nc * 128 + nn) * 8];
        }
        __syncthreads();

        f32x4 acc2[2][4];
        #pragma unroll
        for (int i = 0; i < 2; ++i)
            #pragma unroll
            for (int j = 0; j < 4; ++j) acc2[i][j] = (f32x4){0.f, 0.f, 0.f, 0.f};

        #pragma unroll
        for (int ks = 0; ks < 4; ++ks) {
            bf16x8 h0 = *(const bf16x8*)&Hs[(r2 + lm) * HS_STRIDE + ks * 32 + quad * 8];
            bf16x8 h1 = *(const bf16x8*)&Hs[(r2 + 16 + lm) * HS_STRIDE + ks * 32 + quad * 8];
            #pragma unroll
            for (int tj = 0; tj < 4; ++tj) {
                bf16x8 b = *(const bf16x8*)&Vs[((ks * 4 + quad) * 128 + c2 + tj * 16 + lm) * 8];
                acc2[0][tj] = __builtin_amdgcn_mfma_f32_16x16x32_bf16(h0, b, acc2[0][tj], 0, 0, 0);
                acc2[1][tj] = __builtin_amdgcn_mfma_f32_16x16x32_bf16(h1, b, acc2[1][tj], 0, 0, 0);
            }
        }

        #pragma unroll
        for (int ti = 0; ti < 2; ++ti)
            #pragma unroll
            for (int reg = 0; reg < 4; ++reg) {
                int m = r2 + ti * 16 + quad * 4 + reg;
                int tok = toks[m];
                if (tok >= 0) {
                    float* op = out + (size_t)tok * DDIM + nc * 128 + c2 + lm;
                    #pragma unroll
                    for (int tj = 0; tj < 4; ++tj)
                        atomicAdd(op + tj * 16, acc2[ti][tj][reg]);
                }
            }
    }
}

extern "C" void kernel_launch(void* const* d_in, const int* in_sizes, int n_in,
                              void* d_out, int out_size, void* d_ws, size_t ws_size,
                              hipStream_t stream) {
    const float* x      = (const float*)d_in[0];
    const float* es     = (const float*)d_in[1];
    const float* keys   = (const float*)d_in[2];
    const float* values = (const float*)d_in[3];
    float* out          = (float*)d_out;

    // workspace layout (~17.2 MB)
    char* w = (char*)d_ws;
    int*   cnt      = (int*)w;                       w += 256;
    int*   tok_list = (int*)w;                       w += (size_t)NEXP * NTOK * sizeof(int);   // 1 MB
    float* gates    = (float*)w;                     w += (size_t)NTOK * TOPK * sizeof(float); // 128 KB
    unsigned short* Kb = (unsigned short*)w;         w += (size_t)NEXP * 128 * 128 * 8 * 2;    // 8 MB
    unsigned short* Vb = (unsigned short*)w;         // 8 MB

    hipMemsetAsync(cnt, 0, NEXP * sizeof(int), stream);
    hipMemsetAsync(out, 0, (size_t)out_size * sizeof(float), stream);

    prep_weights<<<4096, 256, 0, stream>>>(keys, values, Kb, Vb);
    gate_topk2<<<NTOK / 64, 256, 0, stream>>>(x, es, cnt, tok_list, gates);

    dim3 grid(NTOK / TILE, NEXP);
    expert_ffn_mfma<<<grid, 256, 0, stream>>>(x, Kb, Vb, cnt, tok_list, gates, out);
}

// Round 4
// 352.761 us; speedup vs baseline: 2.3974x; 1.0122x over previous
//
#include <hip/hip_runtime.h>
#include <hip/hip_bf16.h>

#define NTOK 8192   // B*S
#define DDIM 1024
#define NEXP 32
#define HDIM 128
#define TOPK 4

typedef __attribute__((ext_vector_type(8))) short bf16x8;
typedef __attribute__((ext_vector_type(4))) float f32x4;

typedef unsigned int uint_g __attribute__((address_space(1)));
typedef unsigned int uint_l __attribute__((address_space(3)));

// async 16B/lane global->LDS; lds dest must be wave-uniform (HW adds lane*16)
__device__ __forceinline__ void async_cp16(const void* g, void* l) {
    __builtin_amdgcn_global_load_lds((const uint_g*)g, (uint_l*)l, 16, 0, 0);
}

__device__ inline unsigned short f2bf(float f) {
    unsigned int u = __builtin_bit_cast(unsigned int, f);
    unsigned int r = (u + 0x7fffu + ((u >> 16) & 1u)) >> 16;   // RNE
    return (unsigned short)r;
}

// ---------------- Kernel P: convert K/V to bf16 in MFMA-B layout ----------------
// Kb[e][k>>3][n][k&7] for keys [E][D=1024 k][H=128 n]
// Vb[e][k>>3][n][k&7] for values [E][H=128 k][D=1024 n]
__global__ __launch_bounds__(256) void prep_weights(
    const float* __restrict__ keys, const float* __restrict__ values,
    unsigned short* __restrict__ Kb, unsigned short* __restrict__ Vb)
{
    int idx = blockIdx.x * 256 + threadIdx.x;
    unsigned short o[8];
    if (idx < NEXP * 128 * 128) {            // keys: (e, k0 [128], n [128])
        int n = idx & 127, k0 = (idx >> 7) & 127, e = idx >> 14;
        const float* s = keys + ((size_t)e * DDIM + k0 * 8) * HDIM + n;
        #pragma unroll
        for (int j = 0; j < 8; ++j) o[j] = f2bf(s[(size_t)j * HDIM]);
        *(uint4*)&Kb[(size_t)idx * 8] = *(uint4*)o;
    } else {
        idx -= NEXP * 128 * 128;             // values: (e, k0 [16], n [1024])
        int n = idx & 1023, k0 = (idx >> 10) & 15, e = idx >> 14;
        const float* s = values + ((size_t)e * HDIM + k0 * 8) * DDIM + n;
        #pragma unroll
        for (int j = 0; j < 8; ++j) o[j] = f2bf(s[(size_t)j * DDIM]);
        *(uint4*)&Vb[(size_t)idx * 8] = *(uint4*)o;
    }
}

// ---------------- Kernel 1: gating logits (fp32) + top-4 + scatter ----------------
// 64 tokens/block; transposed LDS tiles so inner d-step = b128 + b64 -> 8 FMA
__global__ __launch_bounds__(256) void gate_topk3(
    const float* __restrict__ x, const float* __restrict__ es,
    int* __restrict__ cnt, int* __restrict__ tok_list, float* __restrict__ gates)
{
    const int n0  = blockIdx.x * 64;
    const int tid = threadIdx.x;

    __shared__ float Xt[64 * 68];   // [d][t], stride 68 (16B aligned rows)
    __shared__ float Est[64 * 34];  // [d][e], stride 34 (8B aligned rows)
    __shared__ float Ls[64 * 33];   // logits [t][e]

    const int t4 = (tid & 15) * 4;  // 4 tokens
    const int eg = tid >> 4;        // expert pair 2eg, 2eg+1
    const int xr = tid >> 2, xc = (tid & 3) * 16;
    const int ee = tid >> 3, ed = (tid & 7) * 8;

    float acc[4][2] = {};

    for (int dc = 0; dc < DDIM; dc += 64) {
        __syncthreads();
        #pragma unroll
        for (int i = 0; i < 4; ++i) {
            float4 v = *(const float4*)&x[(size_t)(n0 + xr) * DDIM + dc + xc + i * 4];
            Xt[(xc + i * 4 + 0) * 68 + xr] = v.x;
            Xt[(xc + i * 4 + 1) * 68 + xr] = v.y;
            Xt[(xc + i * 4 + 2) * 68 + xr] = v.z;
            Xt[(xc + i * 4 + 3) * 68 + xr] = v.w;
        }
        #pragma unroll
        for (int i = 0; i < 2; ++i) {
            float4 v = *(const float4*)&es[(size_t)ee * DDIM + dc + ed + i * 4];
            Est[(ed + i * 4 + 0) * 34 + ee] = v.x;
            Est[(ed + i * 4 + 1) * 34 + ee] = v.y;
            Est[(ed + i * 4 + 2) * 34 + ee] = v.z;
            Est[(ed + i * 4 + 3) * 34 + ee] = v.w;
        }
        __syncthreads();

        #pragma unroll 8
        for (int d = 0; d < 64; ++d) {
            float4 xv = *(const float4*)&Xt[d * 68 + t4];
            float2 ev = *(const float2*)&Est[d * 34 + eg * 2];
            acc[0][0] = fmaf(xv.x, ev.x, acc[0][0]); acc[0][1] = fmaf(xv.x, ev.y, acc[0][1]);
            acc[1][0] = fmaf(xv.y, ev.x, acc[1][0]); acc[1][1] = fmaf(xv.y, ev.y, acc[1][1]);
            acc[2][0] = fmaf(xv.z, ev.x, acc[2][0]); acc[2][1] = fmaf(xv.z, ev.y, acc[2][1]);
            acc[3][0] = fmaf(xv.w, ev.x, acc[3][0]); acc[3][1] = fmaf(xv.w, ev.y, acc[3][1]);
        }
    }

    #pragma unroll
    for (int i = 0; i < 4; ++i) {
        Ls[(t4 + i) * 33 + eg * 2 + 0] = acc[i][0];
        Ls[(t4 + i) * 33 + eg * 2 + 1] = acc[i][1];
    }
    __syncthreads();

    if (tid < 64) {
        int n = n0 + tid;
        float lg[NEXP];
        #pragma unroll
        for (int e = 0; e < NEXP; ++e) lg[e] = Ls[tid * 33 + e];
        #pragma unroll
        for (int j = 0; j < TOPK; ++j) {
            int bi = 0; float bv = lg[0];
            for (int e = 1; e < NEXP; ++e)
                if (lg[e] > bv) { bv = lg[e]; bi = e; }   // strict >: lowest index on ties
            lg[bi] = -3.0e38f;
            gates[n * TOPK + j] = 1.f / (1.f + expf(-bv));
            int pos = atomicAdd(&cnt[bi], 1);
            tok_list[(size_t)bi * NTOK + pos] = n * TOPK + j;   // packed slot id
        }
    }
}

// ---------------- Kernel F1: H = relu(X_tile @ K_e) * gate -> Hb (bf16) ----------------
// grid (32 tiles, 32 experts); 64 tokens x 128 H, BK=64, global_load_lds for K
__global__ __launch_bounds__(256) void ffn_phase1(
    const float* __restrict__ x,
    const unsigned short* __restrict__ Kb,   // [E][128][128][8]
    const int* __restrict__ cnt, const int* __restrict__ tok_list,
    const float* __restrict__ gates,
    unsigned short* __restrict__ Hb)         // [N*4][128]
{
    const int e = blockIdx.y, tile = blockIdx.x;
    const int c = cnt[e], base = tile * 64;
    if (base >= c) return;
    const int nt   = min(64, c - base);
    const int tid  = threadIdx.x, wave = tid >> 6, lane = tid & 63;
    const int lm   = lane & 15, quad = lane >> 4;
    const int r2   = (wave >> 1) * 32, c2 = (wave & 1) * 64;

    __shared__ __align__(16) unsigned short Xs[64 * 72];  // pad 72 (stride 144B = 9x16)
    __shared__ __align__(16) unsigned short Ks[8192];     // contiguous (async dest)
    __shared__ int toks[64], slot[64];
    __shared__ float gs[64];

    if (tid < 64) {
        if (tid < nt) {
            int v = tok_list[(size_t)e * NTOK + base + tid];
            slot[tid] = v; toks[tid] = v >> 2; gs[tid] = gates[v];
        } else { slot[tid] = -1; toks[tid] = -1; gs[tid] = 0.f; }
    }
    __syncthreads();

    const unsigned short* Ke = Kb + (size_t)e * 131072;
    const int xr = tid >> 2, xc = (tid & 3) * 16;
    const int xtok = toks[xr];
    const float* xrow = x + (size_t)(xtok < 0 ? 0 : xtok) * DDIM;

    f32x4 acc[2][4];
    #pragma unroll
    for (int i = 0; i < 2; ++i)
        #pragma unroll
        for (int j = 0; j < 4; ++j) acc[i][j] = (f32x4){0.f, 0.f, 0.f, 0.f};

    for (int dc = 0; dc < DDIM; dc += 64) {
        __syncthreads();                     // prior frag reads done
        #pragma unroll
        for (int i = 0; i < 4; ++i) {        // K chunk 16KB: 4 async/wave
            int u = wave * 4 + i;
            async_cp16(Ke + (size_t)dc * 128 + u * 512 + lane * 8, Ks + u * 512);
        }
        {                                    // X chunk: gather rows, cvt bf16
            float vv[16] = {};
            if (xtok >= 0) {
                #pragma unroll
                for (int i = 0; i < 4; ++i) {
                    float4 v = *(const float4*)&xrow[dc + xc + i * 4];
                    vv[i*4+0] = v.x; vv[i*4+1] = v.y; vv[i*4+2] = v.z; vv[i*4+3] = v.w;
                }
            }
            unsigned short p[16];
            #pragma unroll
            for (int i = 0; i < 16; ++i) p[i] = f2bf(vv[i]);
            *(uint4*)&Xs[xr * 72 + xc]     = ((const uint4*)p)[0];
            *(uint4*)&Xs[xr * 72 + xc + 8] = ((const uint4*)p)[1];
        }
        __syncthreads();                     // compiler drains vmcnt here

        #pragma unroll
        for (int ks = 0; ks < 2; ++ks) {
            bf16x8 a0 = *(const bf16x8*)&Xs[(r2 + lm) * 72 + ks * 32 + quad * 8];
            bf16x8 a1 = *(const bf16x8*)&Xs[(r2 + 16 + lm) * 72 + ks * 32 + quad * 8];
            #pragma unroll
            for (int tj = 0; tj < 4; ++tj) {
                bf16x8 b = *(const bf16x8*)&Ks[((ks * 4 + quad) * 128 + c2 + tj * 16 + lm) * 8];
                acc[0][tj] = __builtin_amdgcn_mfma_f32_16x16x32_bf16(a0, b, acc[0][tj], 0, 0, 0);
                acc[1][tj] = __builtin_amdgcn_mfma_f32_16x16x32_bf16(a1, b, acc[1][tj], 0, 0, 0);
            }
        }
    }

    // epilogue: relu * gate -> bf16 -> Hb[slot][col]
    #pragma unroll
    for (int ti = 0; ti < 2; ++ti)
        #pragma unroll
        for (int reg = 0; reg < 4; ++reg) {
            int m = r2 + ti * 16 + quad * 4 + reg;
            int s = slot[m];
            if (s >= 0) {
                float g = gs[m];
                unsigned short* hp = Hb + (size_t)s * HDIM;
                #pragma unroll
                for (int tj = 0; tj < 4; ++tj)
                    hp[c2 + tj * 16 + lm] = f2bf(fmaxf(acc[ti][tj][reg], 0.f) * g);
            }
        }
}

// ---------------- Kernel F2: out += H_tile @ V_e (K=128 one shot) ----------------
// grid (32 tiles, 8 nc, 32 experts); 64 slots x 128 D-cols; atomics only at end
__global__ __launch_bounds__(256) void ffn_phase2(
    const unsigned short* __restrict__ Hb,   // [N*4][128]
    const unsigned short* __restrict__ Vb,   // [E][16][1024][8]
    const int* __restrict__ cnt, const int* __restrict__ tok_list,
    float* __restrict__ out)                 // [N,D] pre-zeroed
{
    const int e = blockIdx.z, nc = blockIdx.y, tile = blockIdx.x;
    const int c = cnt[e], base = tile * 64;
    if (base >= c) return;
    const int nt   = min(64, c - base);
    const int tid  = threadIdx.x, wave = tid >> 6, lane = tid & 63;
    const int lm   = lane & 15, quad = lane >> 4;
    const int r2   = (wave >> 1) * 32, c2 = (wave & 1) * 64;

    __shared__ __align__(16) unsigned short Hs[64 * 136];  // stride 272B = 17x16
    __shared__ __align__(16) unsigned short Vs[16384];     // [16 k0][128 n][8]
    __shared__ int toks[64], slot[64];

    if (tid < 64) {
        if (tid < nt) {
            int v = tok_list[(size_t)e * NTOK + base + tid];
            slot[tid] = v; toks[tid] = v >> 2;
        } else { slot[tid] = -1; toks[tid] = -1; }
    }
    __syncthreads();

    const unsigned short* Ve = Vb + (size_t)e * 131072;
    #pragma unroll
    for (int i = 0; i < 8; ++i) {            // V chunk 32KB: 8 async/wave
        int u = wave * 8 + i;                // 0..31; piece = (k0, half)
        int k0 = u >> 1, half = u & 1;
        async_cp16(Ve + ((size_t)k0 * 1024 + nc * 128 + half * 64 + lane) * 8,
                   Vs + u * 512);
    }
    {                                        // H tile: gather 64 rows x 256B
        const int hr = tid >> 2, part = tid & 3;
        int s = slot[hr];
        uint4 z = {0u, 0u, 0u, 0u};
        uint4 d0 = z, d1 = z, d2 = z, d3 = z;
        if (s >= 0) {
            const uint4* src = (const uint4*)(Hb + (size_t)s * HDIM + part * 32);
            d0 = src[0]; d1 = src[1]; d2 = src[2]; d3 = src[3];
        }
        uint4* dst = (uint4*)&Hs[hr * 136 + part * 32];
        dst[0] = d0; dst[1] = d1; dst[2] = d2; dst[3] = d3;
    }
    __syncthreads();

    f32x4 acc[2][4];
    #pragma unroll
    for (int i = 0; i < 2; ++i)
        #pragma unroll
        for (int j = 0; j < 4; ++j) acc[i][j] = (f32x4){0.f, 0.f, 0.f, 0.f};

    #pragma unroll
    for (int ks = 0; ks < 4; ++ks) {
        bf16x8 a0 = *(const bf16x8*)&Hs[(r2 + lm) * 136 + ks * 32 + quad * 8];
        bf16x8 a1 = *(const bf16x8*)&Hs[(r2 + 16 + lm) * 136 + ks * 32 + quad * 8];
        #pragma unroll
        for (int tj = 0; tj < 4; ++tj) {
            bf16x8 b = *(const bf16x8*)&Vs[((ks * 4 + quad) * 128 + c2 + tj * 16 + lm) * 8];
            acc[0][tj] = __builtin_amdgcn_mfma_f32_16x16x32_bf16(a0, b, acc[0][tj], 0, 0, 0);
            acc[1][tj] = __builtin_amdgcn_mfma_f32_16x16x32_bf16(a1, b, acc[1][tj], 0, 0, 0);
        }
    }

    // epilogue: free-running atomics, kernel-end drain only
    #pragma unroll
    for (int ti = 0; ti < 2; ++ti)
        #pragma unroll
        for (int reg = 0; reg < 4; ++reg) {
            int m = r2 + ti * 16 + quad * 4 + reg;
            int tok = toks[m];
            if (tok >= 0) {
                float* op = out + (size_t)tok * DDIM + nc * 128 + c2 + lm;
                #pragma unroll
                for (int tj = 0; tj < 4; ++tj)
                    atomicAdd(op + tj * 16, acc[ti][tj][reg]);
            }
        }
}

extern "C" void kernel_launch(void* const* d_in, const int* in_sizes, int n_in,
                              void* d_out, int out_size, void* d_ws, size_t ws_size,
                              hipStream_t stream) {
    const float* x      = (const float*)d_in[0];
    const float* es     = (const float*)d_in[1];
    const float* keys   = (const float*)d_in[2];
    const float* values = (const float*)d_in[3];
    float* out          = (float*)d_out;

    // workspace layout (~25.6 MB)
    char* w = (char*)d_ws;
    int*   cnt      = (int*)w;               w += 256;
    int*   tok_list = (int*)w;               w += (size_t)NEXP * NTOK * sizeof(int);    // 1 MB
    float* gates    = (float*)w;             w += (size_t)NTOK * TOPK * sizeof(float);  // 128 KB
    unsigned short* Kb = (unsigned short*)w; w += (size_t)NEXP * 128 * 128 * 8 * 2;     // 8 MB
    unsigned short* Vb = (unsigned short*)w; w += (size_t)NEXP * 16 * 1024 * 8 * 2;     // 8 MB
    unsigned short* Hb = (unsigned short*)w;                                            // 8.4 MB

    hipMemsetAsync(cnt, 0, NEXP * sizeof(int), stream);
    hipMemsetAsync(out, 0, (size_t)out_size * sizeof(float), stream);

    prep_weights<<<4096, 256, 0, stream>>>(keys, values, Kb, Vb);
    gate_topk3<<<NTOK / 64, 256, 0, stream>>>(x, es, cnt, tok_list, gates);

    ffn_phase1<<<dim3(32, NEXP), 256, 0, stream>>>(x, Kb, cnt, tok_list, gates, Hb);
    ffn_phase2<<<dim3(32, 8, NEXP), 256, 0, stream>>>(Hb, Vb, cnt, tok_list, out);
}

// Round 5
// 283.217 us; speedup vs baseline: 2.9861x; 1.2456x over previous
//
#include <hip/hip_runtime.h>
#include <hip/hip_bf16.h>

#define NTOK 8192   // B*S
#define DDIM 1024
#define NEXP 32
#define HDIM 128
#define TOPK 4

typedef __attribute__((ext_vector_type(8))) short bf16x8;
typedef __attribute__((ext_vector_type(4))) float f32x4;

typedef unsigned int uint_g __attribute__((address_space(1)));
typedef unsigned int uint_l __attribute__((address_space(3)));

// async 16B/lane global->LDS; lds dest wave-uniform (HW adds lane*16)
__device__ __forceinline__ void async_cp16(const void* g, void* l) {
    __builtin_amdgcn_global_load_lds((const uint_g*)g, (uint_l*)l, 16, 0, 0);
}

__device__ inline unsigned short f2bf(float f) {
    unsigned int u = __builtin_bit_cast(unsigned int, f);
    unsigned int r = (u + 0x7fffu + ((u >> 16) & 1u)) >> 16;   // RNE
    return (unsigned short)r;
}
__device__ inline float bf2f(unsigned short s) {
    unsigned int u = ((unsigned int)s) << 16;
    return __builtin_bit_cast(float, u);
}

// ---------------- Kernel P: convert K/V to bf16 in MFMA-B layout ----------------
__global__ __launch_bounds__(256) void prep_weights(
    const float* __restrict__ keys, const float* __restrict__ values,
    unsigned short* __restrict__ Kb, unsigned short* __restrict__ Vb)
{
    int idx = blockIdx.x * 256 + threadIdx.x;
    unsigned short o[8];
    if (idx < NEXP * 128 * 128) {            // keys: (e, k0 [128], n [128])
        int n = idx & 127, k0 = (idx >> 7) & 127, e = idx >> 14;
        const float* s = keys + ((size_t)e * DDIM + k0 * 8) * HDIM + n;
        #pragma unroll
        for (int j = 0; j < 8; ++j) o[j] = f2bf(s[(size_t)j * HDIM]);
        *(uint4*)&Kb[(size_t)idx * 8] = *(uint4*)o;
    } else {
        idx -= NEXP * 128 * 128;             // values: (e, k0 [16], n [1024])
        int n = idx & 1023, k0 = (idx >> 10) & 15, e = idx >> 14;
        const float* s = values + ((size_t)e * HDIM + k0 * 8) * DDIM + n;
        #pragma unroll
        for (int j = 0; j < 8; ++j) o[j] = f2bf(s[(size_t)j * DDIM]);
        *(uint4*)&Vb[(size_t)idx * 8] = *(uint4*)o;
    }
}

// ---------------- Kernel 1: gating (fp32) + top-4 + scatter ----------------
// 512 blocks x 16 tokens; thread = (4 tok) x (4 exp) x (d-replica of 8)
__global__ __launch_bounds__(256) void gate_topk4(
    const float* __restrict__ x, const float* __restrict__ es,
    int* __restrict__ cnt, int* __restrict__ tok_list, float* __restrict__ gates)
{
    const int n0  = blockIdx.x * 16;
    const int tid = threadIdx.x;

    __shared__ float Xt[64 * 36];     // [d][tok], stride 36 (2-way max on r/w)
    __shared__ float Est[64 * 36];    // [d][e]
    __shared__ float Lp[8 * 16 * 33]; // partials [rep][tok][e]
    __shared__ float Ls[16 * 33];

    const int t4  = (tid & 3) * 4;          // 4 tokens
    const int e4  = ((tid >> 2) & 7) * 4;   // 4 experts
    const int rep = tid >> 5;               // d-replica 0..7

    const int xr = tid & 15, xc4 = (tid >> 4) * 4;     // X staging
    const int er = tid & 31, ec8 = (tid >> 5) * 8;     // es staging

    float acc[4][4] = {};

    for (int dc = 0; dc < DDIM; dc += 64) {
        __syncthreads();
        {
            float4 v = *(const float4*)&x[(size_t)(n0 + xr) * DDIM + dc + xc4];
            Xt[(xc4 + 0) * 36 + xr] = v.x; Xt[(xc4 + 1) * 36 + xr] = v.y;
            Xt[(xc4 + 2) * 36 + xr] = v.z; Xt[(xc4 + 3) * 36 + xr] = v.w;
        }
        #pragma unroll
        for (int i = 0; i < 2; ++i) {
            float4 v = *(const float4*)&es[(size_t)er * DDIM + dc + ec8 + i * 4];
            Est[(ec8 + i * 4 + 0) * 36 + er] = v.x;
            Est[(ec8 + i * 4 + 1) * 36 + er] = v.y;
            Est[(ec8 + i * 4 + 2) * 36 + er] = v.z;
            Est[(ec8 + i * 4 + 3) * 36 + er] = v.w;
        }
        __syncthreads();

        #pragma unroll
        for (int s = 0; s < 8; ++s) {
            int d = s * 8 + rep;
            float4 xv = *(const float4*)&Xt[d * 36 + t4];
            float4 ev = *(const float4*)&Est[d * 36 + e4];
            const float xa[4] = {xv.x, xv.y, xv.z, xv.w};
            const float ea[4] = {ev.x, ev.y, ev.z, ev.w};
            #pragma unroll
            for (int i = 0; i < 4; ++i)
                #pragma unroll
                for (int j = 0; j < 4; ++j)
                    acc[i][j] = fmaf(xa[i], ea[j], acc[i][j]);
        }
    }

    __syncthreads();
    #pragma unroll
    for (int i = 0; i < 4; ++i)
        #pragma unroll
        for (int j = 0; j < 4; ++j)
            Lp[(rep * 16 + t4 + i) * 33 + e4 + j] = acc[i][j];
    __syncthreads();

    for (int p = tid; p < 16 * 32; p += 256) {
        int tok = p >> 5, e = p & 31;
        float s = 0.f;
        #pragma unroll
        for (int r = 0; r < 8; ++r) s += Lp[(r * 16 + tok) * 33 + e];
        Ls[tok * 33 + e] = s;
    }
    __syncthreads();

    if (tid < 16) {
        int n = n0 + tid;
        float lg[NEXP];
        #pragma unroll
        for (int e = 0; e < NEXP; ++e) lg[e] = Ls[tid * 33 + e];
        #pragma unroll
        for (int j = 0; j < TOPK; ++j) {
            int bi = 0; float bv = lg[0];
            for (int e = 1; e < NEXP; ++e)
                if (lg[e] > bv) { bv = lg[e]; bi = e; }   // strict >: lowest idx on ties
            lg[bi] = -3.0e38f;
            gates[n * TOPK + j] = 1.f / (1.f + expf(-bv));
            int pos = atomicAdd(&cnt[bi], 1);
            tok_list[(size_t)bi * NTOK + pos] = n * TOPK + j;   // packed slot id
        }
    }
}

// ---------------- Kernel F1: Hb[slot] = relu(X_tile @ K_e) * gate (bf16) ----------------
// grid (64 tiles, 32 experts); 32 tokens x 128 H, BK=64
__global__ __launch_bounds__(256) void ffn_phase1(
    const float* __restrict__ x,
    const unsigned short* __restrict__ Kb,   // [E][128][128][8]
    const int* __restrict__ cnt, const int* __restrict__ tok_list,
    const float* __restrict__ gates,
    unsigned short* __restrict__ Hb)         // [N*4][128]
{
    const int e = blockIdx.y, tile = blockIdx.x;
    const int c = cnt[e], base = tile * 32;
    if (base >= c) return;
    const int nt   = min(32, c - base);
    const int tid  = threadIdx.x, wave = tid >> 6, lane = tid & 63;
    const int lm   = lane & 15, quad = lane >> 4;
    const int r2   = (wave >> 1) * 16, c2 = (wave & 1) * 64;

    __shared__ __align__(16) unsigned short Xs[32 * 72];  // 4.6 KB
    __shared__ __align__(16) unsigned short Ks[8192];     // 16 KB (async dest)
    __shared__ int slot[32];
    __shared__ int toks[32];
    __shared__ float gs[32];

    if (tid < 32) {
        if (tid < nt) {
            int v = tok_list[(size_t)e * NTOK + base + tid];
            slot[tid] = v; toks[tid] = v >> 2; gs[tid] = gates[v];
        } else { slot[tid] = -1; toks[tid] = -1; gs[tid] = 0.f; }
    }
    __syncthreads();

    const unsigned short* Ke = Kb + (size_t)e * 131072;
    const int xr = tid >> 3, xseg = (tid & 7) * 8;
    const int xtok = toks[xr];
    const float* xrow = x + (size_t)(xtok < 0 ? 0 : xtok) * DDIM;

    f32x4 acc[4];
    #pragma unroll
    for (int j = 0; j < 4; ++j) acc[j] = (f32x4){0.f, 0.f, 0.f, 0.f};

    for (int dc = 0; dc < DDIM; dc += 64) {
        __syncthreads();                     // prior frag reads done
        #pragma unroll
        for (int i = 0; i < 4; ++i) {        // K chunk 16KB: 4 async/wave
            int u = wave * 4 + i;
            async_cp16(Ke + (size_t)dc * 128 + u * 512 + lane * 8, Ks + u * 512);
        }
        {                                    // X chunk: gather row, cvt bf16 (16B/thread)
            float4 v0 = make_float4(0.f,0.f,0.f,0.f), v1 = v0;
            if (xtok >= 0) {
                v0 = *(const float4*)&xrow[dc + xseg];
                v1 = *(const float4*)&xrow[dc + xseg + 4];
            }
            unsigned short p[8] = { f2bf(v0.x), f2bf(v0.y), f2bf(v0.z), f2bf(v0.w),
                                    f2bf(v1.x), f2bf(v1.y), f2bf(v1.z), f2bf(v1.w) };
            *(uint4*)&Xs[xr * 72 + xseg] = *(uint4*)p;
        }
        __syncthreads();                     // drains vmcnt (async K) too

        #pragma unroll
        for (int ks = 0; ks < 2; ++ks) {
            bf16x8 a = *(const bf16x8*)&Xs[(r2 + lm) * 72 + ks * 32 + quad * 8];
            #pragma unroll
            for (int tj = 0; tj < 4; ++tj) {
                bf16x8 b = *(const bf16x8*)&Ks[((ks * 4 + quad) * 128 + c2 + tj * 16 + lm) * 8];
                acc[tj] = __builtin_amdgcn_mfma_f32_16x16x32_bf16(a, b, acc[tj], 0, 0, 0);
            }
        }
    }

    // epilogue: relu * gate -> bf16 -> Hb[slot][col]
    #pragma unroll
    for (int reg = 0; reg < 4; ++reg) {
        int m = r2 + quad * 4 + reg;
        int s = slot[m];
        if (s >= 0) {
            float g = gs[m];
            unsigned short* hp = Hb + (size_t)s * HDIM;
            #pragma unroll
            for (int tj = 0; tj < 4; ++tj)
                hp[c2 + tj * 16 + lm] = f2bf(fmaxf(acc[tj][reg], 0.f) * g);
        }
    }
}

// ---------------- Kernel F2: Ob[slot] = Hb[slot] @ V_e (bf16, no atomics) ----------------
// grid (32 tiles, 8 nc, 32 experts); 64 slots x 128 D-cols, K=128 one shot
__global__ __launch_bounds__(256) void ffn_phase2(
    const unsigned short* __restrict__ Hb,   // [N*4][128]
    const unsigned short* __restrict__ Vb,   // [E][16][1024][8]
    const int* __restrict__ cnt, const int* __restrict__ tok_list,
    unsigned short* __restrict__ Ob)         // [N*4][1024] bf16
{
    const int e = blockIdx.z, nc = blockIdx.y, tile = blockIdx.x;
    const int c = cnt[e], base = tile * 64;
    if (base >= c) return;
    const int nt   = min(64, c - base);
    const int tid  = threadIdx.x, wave = tid >> 6, lane = tid & 63;
    const int lm   = lane & 15, quad = lane >> 4;
    const int r2   = (wave >> 1) * 32, c2 = (wave & 1) * 64;

    __shared__ __align__(16) unsigned short Hs[64 * 136];  // 17.4 KB
    __shared__ __align__(16) unsigned short Vs[16384];     // 32 KB (async dest)
    __shared__ int slot[64];

    if (tid < 64) {
        if (tid < nt) slot[tid] = tok_list[(size_t)e * NTOK + base + tid];
        else          slot[tid] = -1;
    }
    __syncthreads();

    const unsigned short* Ve = Vb + (size_t)e * 131072;
    #pragma unroll
    for (int i = 0; i < 8; ++i) {            // V chunk 32KB: 8 async/wave
        int u = wave * 8 + i;                // (k0, half)
        int k0 = u >> 1, half = u & 1;
        async_cp16(Ve + ((size_t)k0 * 1024 + nc * 128 + half * 64 + lane) * 8,
                   Vs + u * 512);
    }
    {                                        // H tile gather: 64 rows x 256B
        const int hr = tid >> 2, part = tid & 3;
        int s = slot[hr];
        uint4 z = {0u, 0u, 0u, 0u};
        uint4 d0 = z, d1 = z, d2 = z, d3 = z;
        if (s >= 0) {
            const uint4* src = (const uint4*)(Hb + (size_t)s * HDIM + part * 32);
            d0 = src[0]; d1 = src[1]; d2 = src[2]; d3 = src[3];
        }
        uint4* dst = (uint4*)&Hs[hr * 136 + part * 32];
        dst[0] = d0; dst[1] = d1; dst[2] = d2; dst[3] = d3;
    }
    __syncthreads();

    f32x4 acc[2][4];
    #pragma unroll
    for (int i = 0; i < 2; ++i)
        #pragma unroll
        for (int j = 0; j < 4; ++j) acc[i][j] = (f32x4){0.f, 0.f, 0.f, 0.f};

    #pragma unroll
    for (int ks = 0; ks < 4; ++ks) {
        bf16x8 a0 = *(const bf16x8*)&Hs[(r2 + lm) * 136 + ks * 32 + quad * 8];
        bf16x8 a1 = *(const bf16x8*)&Hs[(r2 + 16 + lm) * 136 + ks * 32 + quad * 8];
        #pragma unroll
        for (int tj = 0; tj < 4; ++tj) {
            bf16x8 b = *(const bf16x8*)&Vs[((ks * 4 + quad) * 128 + c2 + tj * 16 + lm) * 8];
            acc[0][tj] = __builtin_amdgcn_mfma_f32_16x16x32_bf16(a0, b, acc[0][tj], 0, 0, 0);
            acc[1][tj] = __builtin_amdgcn_mfma_f32_16x16x32_bf16(a1, b, acc[1][tj], 0, 0, 0);
        }
    }

    // epilogue: plain bf16 stores (slot rows are unique -> no atomics)
    #pragma unroll
    for (int ti = 0; ti < 2; ++ti)
        #pragma unroll
        for (int reg = 0; reg < 4; ++reg) {
            int m = r2 + ti * 16 + quad * 4 + reg;
            int s = slot[m];
            if (s >= 0) {
                unsigned short* op = Ob + (size_t)s * DDIM + nc * 128 + c2 + lm;
                #pragma unroll
                for (int tj = 0; tj < 4; ++tj)
                    op[tj * 16] = f2bf(acc[ti][tj][reg]);
            }
        }
}

// ---------------- Kernel R: out[n] = sum_j Ob[4n+j]  (bf16 -> fp32) ----------------
__global__ __launch_bounds__(256) void reduce_out(
    const unsigned short* __restrict__ Ob, float* __restrict__ out)
{
    const int tid = threadIdx.x;
    const int n   = blockIdx.x * 2 + (tid >> 7);
    const int cc  = (tid & 127) * 8;

    float s[8] = {};
    #pragma unroll
    for (int j = 0; j < 4; ++j) {
        uint4 v = *(const uint4*)&Ob[((size_t)n * 4 + j) * DDIM + cc];
        const unsigned int w[4] = {v.x, v.y, v.z, v.w};
        #pragma unroll
        for (int q = 0; q < 4; ++q) {
            s[q * 2 + 0] += bf2f((unsigned short)(w[q] & 0xffff));
            s[q * 2 + 1] += bf2f((unsigned short)(w[q] >> 16));
        }
    }
    float4 o0 = {s[0], s[1], s[2], s[3]};
    float4 o1 = {s[4], s[5], s[6], s[7]};
    *(float4*)&out[(size_t)n * DDIM + cc]     = o0;
    *(float4*)&out[(size_t)n * DDIM + cc + 4] = o1;
}

extern "C" void kernel_launch(void* const* d_in, const int* in_sizes, int n_in,
                              void* d_out, int out_size, void* d_ws, size_t ws_size,
                              hipStream_t stream) {
    const float* x      = (const float*)d_in[0];
    const float* es     = (const float*)d_in[1];
    const float* keys   = (const float*)d_in[2];
    const float* values = (const float*)d_in[3];
    float* out          = (float*)d_out;

    // workspace layout (~93 MB)
    char* w = (char*)d_ws;
    int*   cnt      = (int*)w;               w += 256;
    int*   tok_list = (int*)w;               w += (size_t)NEXP * NTOK * sizeof(int);    // 1 MB
    float* gates    = (float*)w;             w += (size_t)NTOK * TOPK * sizeof(float);  // 128 KB
    unsigned short* Kb = (unsigned short*)w; w += (size_t)NEXP * 128 * 128 * 8 * 2;     // 8 MB
    unsigned short* Vb = (unsigned short*)w; w += (size_t)NEXP * 16 * 1024 * 8 * 2;     // 8 MB
    unsigned short* Hb = (unsigned short*)w; w += (size_t)NTOK * TOPK * HDIM * 2;       // 8.4 MB
    unsigned short* Ob = (unsigned short*)w;                                            // 67 MB

    hipMemsetAsync(cnt, 0, NEXP * sizeof(int), stream);

    prep_weights<<<4096, 256, 0, stream>>>(keys, values, Kb, Vb);
    gate_topk4<<<NTOK / 16, 256, 0, stream>>>(x, es, cnt, tok_list, gates);

    ffn_phase1<<<dim3(64, NEXP), 256, 0, stream>>>(x, Kb, cnt, tok_list, gates, Hb);
    ffn_phase2<<<dim3(32, 8, NEXP), 256, 0, stream>>>(Hb, Vb, cnt, tok_list, Ob);
    reduce_out<<<NTOK / 2, 256, 0, stream>>>(Ob, out);
}

// Round 6
// 279.326 us; speedup vs baseline: 3.0277x; 1.0139x over previous
//
#include <hip/hip_runtime.h>
#include <hip/hip_bf16.h>

#define NTOK 8192   // B*S
#define DDIM 1024
#define NEXP 32
#define HDIM 128
#define TOPK 4

typedef __attribute__((ext_vector_type(8))) short bf16x8;
typedef __attribute__((ext_vector_type(4))) float f32x4;

typedef unsigned int uint_g __attribute__((address_space(1)));
typedef unsigned int uint_l __attribute__((address_space(3)));

// async 16B/lane global->LDS; lds dest wave-uniform (HW adds lane*16)
__device__ __forceinline__ void async_cp16(const void* g, void* l) {
    __builtin_amdgcn_global_load_lds((const uint_g*)g, (uint_l*)l, 16, 0, 0);
}

__device__ inline unsigned short f2bf(float f) {
    unsigned int u = __builtin_bit_cast(unsigned int, f);
    unsigned int r = (u + 0x7fffu + ((u >> 16) & 1u)) >> 16;   // RNE
    return (unsigned short)r;
}
__device__ inline float bf2f(unsigned short s) {
    unsigned int u = ((unsigned int)s) << 16;
    return __builtin_bit_cast(float, u);
}

// ---------------- Kernel P: convert K/V to bf16 in MFMA-B layout ----------------
__global__ __launch_bounds__(256) void prep_weights(
    const float* __restrict__ keys, const float* __restrict__ values,
    unsigned short* __restrict__ Kb, unsigned short* __restrict__ Vb)
{
    int idx = blockIdx.x * 256 + threadIdx.x;
    unsigned short o[8];
    if (idx < NEXP * 128 * 128) {            // keys: (e, k0 [128], n [128])
        int n = idx & 127, k0 = (idx >> 7) & 127, e = idx >> 14;
        const float* s = keys + ((size_t)e * DDIM + k0 * 8) * HDIM + n;
        #pragma unroll
        for (int j = 0; j < 8; ++j) o[j] = f2bf(s[(size_t)j * HDIM]);
        *(uint4*)&Kb[(size_t)idx * 8] = *(uint4*)o;
    } else {
        idx -= NEXP * 128 * 128;             // values: (e, k0 [16], n [1024])
        int n = idx & 1023, k0 = (idx >> 10) & 15, e = idx >> 14;
        const float* s = values + ((size_t)e * HDIM + k0 * 8) * DDIM + n;
        #pragma unroll
        for (int j = 0; j < 8; ++j) o[j] = f2bf(s[(size_t)j * DDIM]);
        *(uint4*)&Vb[(size_t)idx * 8] = *(uint4*)o;
    }
}

// ---------------- Kernel G1: gating partial logits (fp32, deterministic) ----------------
// grid (512 token-tiles, 4 d-chunks); block = 16 tok x 32 exp over 256 d
__global__ __launch_bounds__(256) void gate_partial(
    const float* __restrict__ x, const float* __restrict__ es,
    float* __restrict__ gpart)               // [4][NTOK][32]
{
    const int n0    = blockIdx.x * 16;
    const int dbase = blockIdx.y * 256;
    const int tid   = threadIdx.x;

    // union: staging tiles (4608 fp32) reused as partial buffer (4224 fp32)
    __shared__ float smem[4608];             // 18.4 KB -> 8 blocks/CU
    float* Xt  = smem;                       // [d][tok] stride 36
    float* Est = smem + 64 * 36;             // [d][e]   stride 36

    const int t4  = (tid & 3) * 4;           // 4 tokens
    const int e4  = ((tid >> 2) & 7) * 4;    // 4 experts
    const int rep = tid >> 5;                // d-replica 0..7

    const int xr = tid & 15, xc4 = (tid >> 4) * 4;   // X staging
    const int er = tid & 31, ec8 = (tid >> 5) * 8;   // es staging

    float acc[4][4] = {};

    for (int dc = dbase; dc < dbase + 256; dc += 64) {
        __syncthreads();
        {
            float4 v = *(const float4*)&x[(size_t)(n0 + xr) * DDIM + dc + xc4];
            Xt[(xc4 + 0) * 36 + xr] = v.x; Xt[(xc4 + 1) * 36 + xr] = v.y;
            Xt[(xc4 + 2) * 36 + xr] = v.z; Xt[(xc4 + 3) * 36 + xr] = v.w;
        }
        #pragma unroll
        for (int i = 0; i < 2; ++i) {
            float4 v = *(const float4*)&es[(size_t)er * DDIM + dc + ec8 + i * 4];
            Est[(ec8 + i * 4 + 0) * 36 + er] = v.x;
            Est[(ec8 + i * 4 + 1) * 36 + er] = v.y;
            Est[(ec8 + i * 4 + 2) * 36 + er] = v.z;
            Est[(ec8 + i * 4 + 3) * 36 + er] = v.w;
        }
        __syncthreads();

        #pragma unroll
        for (int s = 0; s < 8; ++s) {
            int d = s * 8 + rep;
            float4 xv = *(const float4*)&Xt[d * 36 + t4];
            float4 ev = *(const float4*)&Est[d * 36 + e4];
            const float xa[4] = {xv.x, xv.y, xv.z, xv.w};
            const float ea[4] = {ev.x, ev.y, ev.z, ev.w};
            #pragma unroll
            for (int i = 0; i < 4; ++i)
                #pragma unroll
                for (int j = 0; j < 4; ++j)
                    acc[i][j] = fmaf(xa[i], ea[j], acc[i][j]);
        }
    }

    __syncthreads();                          // staging tiles dead -> reuse as Lp
    float* Lp = smem;                         // [rep 8][tok 16][e 33]
    #pragma unroll
    for (int i = 0; i < 4; ++i)
        #pragma unroll
        for (int j = 0; j < 4; ++j)
            Lp[(rep * 16 + t4 + i) * 33 + e4 + j] = acc[i][j];
    __syncthreads();

    for (int p = tid; p < 16 * 32; p += 256) {
        int tok = p >> 5, e = p & 31;
        float s = 0.f;
        #pragma unroll
        for (int r = 0; r < 8; ++r) s += Lp[(r * 16 + tok) * 33 + e];
        gpart[((size_t)blockIdx.y * NTOK + n0 + tok) * NEXP + e] = s;
    }
}

// ---------------- Kernel G2: sum partials (fixed order), top-4, scatter ----------------
__global__ __launch_bounds__(64) void topk_scatter(
    const float* __restrict__ gpart,         // [4][NTOK][32]
    int* __restrict__ cnt, int* __restrict__ tok_list, float* __restrict__ gates)
{
    const int n = blockIdx.x * 64 + threadIdx.x;

    float lg[NEXP];
    #pragma unroll
    for (int i = 0; i < 8; ++i) {
        float4 v = *(const float4*)&gpart[(size_t)n * NEXP + i * 4];
        lg[i*4+0] = v.x; lg[i*4+1] = v.y; lg[i*4+2] = v.z; lg[i*4+3] = v.w;
    }
    #pragma unroll
    for (int j = 1; j < 4; ++j)
        #pragma unroll
        for (int i = 0; i < 8; ++i) {
            float4 v = *(const float4*)&gpart[((size_t)j * NTOK + n) * NEXP + i * 4];
            lg[i*4+0] += v.x; lg[i*4+1] += v.y; lg[i*4+2] += v.z; lg[i*4+3] += v.w;
        }

    #pragma unroll
    for (int j = 0; j < TOPK; ++j) {
        int bi = 0; float bv = lg[0];
        #pragma unroll
        for (int e = 1; e < NEXP; ++e)
            if (lg[e] > bv) { bv = lg[e]; bi = e; }   // strict >: lowest idx on ties
        lg[bi] = -3.0e38f;
        gates[n * TOPK + j] = 1.f / (1.f + expf(-bv));
        int pos = atomicAdd(&cnt[bi], 1);
        tok_list[(size_t)bi * NTOK + pos] = n * TOPK + j;   // packed slot id
    }
}

// ---------------- Kernel F1: Hb[slot] = relu(X_tile @ K_e) * gate (bf16) ----------------
// grid (64 tiles, 32 experts); 32 tokens x 128 H, BK=64
__global__ __launch_bounds__(256) void ffn_phase1(
    const float* __restrict__ x,
    const unsigned short* __restrict__ Kb,   // [E][128][128][8]
    const int* __restrict__ cnt, const int* __restrict__ tok_list,
    const float* __restrict__ gates,
    unsigned short* __restrict__ Hb)         // [N*4][128]
{
    const int e = blockIdx.y, tile = blockIdx.x;
    const int c = cnt[e], base = tile * 32;
    if (base >= c) return;
    const int nt   = min(32, c - base);
    const int tid  = threadIdx.x, wave = tid >> 6, lane = tid & 63;
    const int lm   = lane & 15, quad = lane >> 4;
    const int r2   = (wave >> 1) * 16, c2 = (wave & 1) * 64;

    __shared__ __align__(16) unsigned short Xs[32 * 72];  // 4.6 KB
    __shared__ __align__(16) unsigned short Ks[8192];     // 16 KB (async dest)
    __shared__ int slot[32];
    __shared__ int toks[32];
    __shared__ float gs[32];

    if (tid < 32) {
        if (tid < nt) {
            int v = tok_list[(size_t)e * NTOK + base + tid];
            slot[tid] = v; toks[tid] = v >> 2; gs[tid] = gates[v];
        } else { slot[tid] = -1; toks[tid] = -1; gs[tid] = 0.f; }
    }
    __syncthreads();

    const unsigned short* Ke = Kb + (size_t)e * 131072;
    const int xr = tid >> 3, xseg = (tid & 7) * 8;
    const int xtok = toks[xr];
    const float* xrow = x + (size_t)(xtok < 0 ? 0 : xtok) * DDIM;

    f32x4 acc[4];
    #pragma unroll
    for (int j = 0; j < 4; ++j) acc[j] = (f32x4){0.f, 0.f, 0.f, 0.f};

    for (int dc = 0; dc < DDIM; dc += 64) {
        __syncthreads();                     // prior frag reads done
        #pragma unroll
        for (int i = 0; i < 4; ++i) {        // K chunk 16KB: 4 async/wave
            int u = wave * 4 + i;
            async_cp16(Ke + (size_t)dc * 128 + u * 512 + lane * 8, Ks + u * 512);
        }
        {                                    // X chunk: gather row, cvt bf16 (16B/thread)
            float4 v0 = make_float4(0.f,0.f,0.f,0.f), v1 = v0;
            if (xtok >= 0) {
                v0 = *(const float4*)&xrow[dc + xseg];
                v1 = *(const float4*)&xrow[dc + xseg + 4];
            }
            unsigned short p[8] = { f2bf(v0.x), f2bf(v0.y), f2bf(v0.z), f2bf(v0.w),
                                    f2bf(v1.x), f2bf(v1.y), f2bf(v1.z), f2bf(v1.w) };
            *(uint4*)&Xs[xr * 72 + xseg] = *(uint4*)p;
        }
        __syncthreads();                     // drains vmcnt (async K) too

        #pragma unroll
        for (int ks = 0; ks < 2; ++ks) {
            bf16x8 a = *(const bf16x8*)&Xs[(r2 + lm) * 72 + ks * 32 + quad * 8];
            #pragma unroll
            for (int tj = 0; tj < 4; ++tj) {
                bf16x8 b = *(const bf16x8*)&Ks[((ks * 4 + quad) * 128 + c2 + tj * 16 + lm) * 8];
                acc[tj] = __builtin_amdgcn_mfma_f32_16x16x32_bf16(a, b, acc[tj], 0, 0, 0);
            }
        }
    }

    // epilogue: relu * gate -> bf16 -> Hb[slot][col]
    #pragma unroll
    for (int reg = 0; reg < 4; ++reg) {
        int m = r2 + quad * 4 + reg;
        int s = slot[m];
        if (s >= 0) {
            float g = gs[m];
            unsigned short* hp = Hb + (size_t)s * HDIM;
            #pragma unroll
            for (int tj = 0; tj < 4; ++tj)
                hp[c2 + tj * 16 + lm] = f2bf(fmaxf(acc[tj][reg], 0.f) * g);
        }
    }
}

// ---------------- Kernel F2: Ob[slot] = Hb[slot] @ V_e (bf16, no atomics) ----------------
// grid (32 tiles, 8 nc, 32 experts); 64 slots x 128 D-cols, K=128 one shot
__global__ __launch_bounds__(256) void ffn_phase2(
    const unsigned short* __restrict__ Hb,   // [N*4][128]
    const unsigned short* __restrict__ Vb,   // [E][16][1024][8]
    const int* __restrict__ cnt, const int* __restrict__ tok_list,
    unsigned short* __restrict__ Ob)         // [N*4][1024] bf16
{
    const int e = blockIdx.z, nc = blockIdx.y, tile = blockIdx.x;
    const int c = cnt[e], base = tile * 64;
    if (base >= c) return;
    const int nt   = min(64, c - base);
    const int tid  = threadIdx.x, wave = tid >> 6, lane = tid & 63;
    const int lm   = lane & 15, quad = lane >> 4;
    const int r2   = (wave >> 1) * 32, c2 = (wave & 1) * 64;

    __shared__ __align__(16) unsigned short Hs[64 * 136];  // 17.4 KB
    __shared__ __align__(16) unsigned short Vs[16384];     // 32 KB (async dest)
    __shared__ int slot[64];

    if (tid < 64) {
        if (tid < nt) slot[tid] = tok_list[(size_t)e * NTOK + base + tid];
        else          slot[tid] = -1;
    }
    __syncthreads();

    const unsigned short* Ve = Vb + (size_t)e * 131072;
    #pragma unroll
    for (int i = 0; i < 8; ++i) {            // V chunk 32KB: 8 async/wave
        int u = wave * 8 + i;                // (k0, half)
        int k0 = u >> 1, half = u & 1;
        async_cp16(Ve + ((size_t)k0 * 1024 + nc * 128 + half * 64 + lane) * 8,
                   Vs + u * 512);
    }
    {                                        // H tile gather: 64 rows x 256B
        const int hr = tid >> 2, part = tid & 3;
        int s = slot[hr];
        uint4 z = {0u, 0u, 0u, 0u};
        uint4 d0 = z, d1 = z, d2 = z, d3 = z;
        if (s >= 0) {
            const uint4* src = (const uint4*)(Hb + (size_t)s * HDIM + part * 32);
            d0 = src[0]; d1 = src[1]; d2 = src[2]; d3 = src[3];
        }
        uint4* dst = (uint4*)&Hs[hr * 136 + part * 32];
        dst[0] = d0; dst[1] = d1; dst[2] = d2; dst[3] = d3;
    }
    __syncthreads();

    f32x4 acc[2][4];
    #pragma unroll
    for (int i = 0; i < 2; ++i)
        #pragma unroll
        for (int j = 0; j < 4; ++j) acc[i][j] = (f32x4){0.f, 0.f, 0.f, 0.f};

    #pragma unroll
    for (int ks = 0; ks < 4; ++ks) {
        bf16x8 a0 = *(const bf16x8*)&Hs[(r2 + lm) * 136 + ks * 32 + quad * 8];
        bf16x8 a1 = *(const bf16x8*)&Hs[(r2 + 16 + lm) * 136 + ks * 32 + quad * 8];
        #pragma unroll
        for (int tj = 0; tj < 4; ++tj) {
            bf16x8 b = *(const bf16x8*)&Vs[((ks * 4 + quad) * 128 + c2 + tj * 16 + lm) * 8];
            acc[0][tj] = __builtin_amdgcn_mfma_f32_16x16x32_bf16(a0, b, acc[0][tj], 0, 0, 0);
            acc[1][tj] = __builtin_amdgcn_mfma_f32_16x16x32_bf16(a1, b, acc[1][tj], 0, 0, 0);
        }
    }

    // epilogue: plain bf16 stores (slot rows are unique -> no atomics)
    #pragma unroll
    for (int ti = 0; ti < 2; ++ti)
        #pragma unroll
        for (int reg = 0; reg < 4; ++reg) {
            int m = r2 + ti * 16 + quad * 4 + reg;
            int s = slot[m];
            if (s >= 0) {
                unsigned short* op = Ob + (size_t)s * DDIM + nc * 128 + c2 + lm;
                #pragma unroll
                for (int tj = 0; tj < 4; ++tj)
                    op[tj * 16] = f2bf(acc[ti][tj][reg]);
            }
        }
}

// ---------------- Kernel R: out[n] = sum_j Ob[4n+j]  (bf16 -> fp32) ----------------
__global__ __launch_bounds__(256) void reduce_out(
    const unsigned short* __restrict__ Ob, float* __restrict__ out)
{
    const int tid = threadIdx.x;
    const int n   = blockIdx.x * 2 + (tid >> 7);
    const int cc  = (tid & 127) * 8;

    float s[8] = {};
    #pragma unroll
    for (int j = 0; j < 4; ++j) {
        uint4 v = *(const uint4*)&Ob[((size_t)n * 4 + j) * DDIM + cc];
        const unsigned int w[4] = {v.x, v.y, v.z, v.w};
        #pragma unroll
        for (int q = 0; q < 4; ++q) {
            s[q * 2 + 0] += bf2f((unsigned short)(w[q] & 0xffff));
            s[q * 2 + 1] += bf2f((unsigned short)(w[q] >> 16));
        }
    }
    float4 o0 = {s[0], s[1], s[2], s[3]};
    float4 o1 = {s[4], s[5], s[6], s[7]};
    *(float4*)&out[(size_t)n * DDIM + cc]     = o0;
    *(float4*)&out[(size_t)n * DDIM + cc + 4] = o1;
}

extern "C" void kernel_launch(void* const* d_in, const int* in_sizes, int n_in,
                              void* d_out, int out_size, void* d_ws, size_t ws_size,
                              hipStream_t stream) {
    const float* x      = (const float*)d_in[0];
    const float* es     = (const float*)d_in[1];
    const float* keys   = (const float*)d_in[2];
    const float* values = (const float*)d_in[3];
    float* out          = (float*)d_out;

    // workspace layout (~97 MB)
    char* w = (char*)d_ws;
    int*   cnt      = (int*)w;               w += 256;
    int*   tok_list = (int*)w;               w += (size_t)NEXP * NTOK * sizeof(int);    // 1 MB
    float* gates    = (float*)w;             w += (size_t)NTOK * TOPK * sizeof(float);  // 128 KB
    float* gpart    = (float*)w;             w += (size_t)4 * NTOK * NEXP * sizeof(float); // 4 MB
    unsigned short* Kb = (unsigned short*)w; w += (size_t)NEXP * 128 * 128 * 8 * 2;     // 8 MB
    unsigned short* Vb = (unsigned short*)w; w += (size_t)NEXP * 16 * 1024 * 8 * 2;     // 8 MB
    unsigned short* Hb = (unsigned short*)w; w += (size_t)NTOK * TOPK * HDIM * 2;       // 8.4 MB
    unsigned short* Ob = (unsigned short*)w;                                            // 67 MB

    hipMemsetAsync(cnt, 0, NEXP * sizeof(int), stream);

    prep_weights<<<4096, 256, 0, stream>>>(keys, values, Kb, Vb);
    gate_partial<<<dim3(NTOK / 16, 4), 256, 0, stream>>>(x, es, gpart);
    topk_scatter<<<NTOK / 64, 64, 0, stream>>>(gpart, cnt, tok_list, gates);

    ffn_phase1<<<dim3(64, NEXP), 256, 0, stream>>>(x, Kb, cnt, tok_list, gates, Hb);
    ffn_phase2<<<dim3(32, 8, NEXP), 256, 0, stream>>>(Hb, Vb, cnt, tok_list, Ob);
    reduce_out<<<NTOK / 2, 256, 0, stream>>>(Ob, out);
}

// Round 7
// 221.102 us; speedup vs baseline: 3.8250x; 1.2633x over previous
//
#include <hip/hip_runtime.h>
#include <hip/hip_bf16.h>

#define NTOK 8192   // B*S
#define DDIM 1024
#define NEXP 32
#define HDIM 128
#define TOPK 4

typedef __attribute__((ext_vector_type(8))) short bf16x8;
typedef __attribute__((ext_vector_type(4))) float f32x4;

typedef unsigned int uint_g __attribute__((address_space(1)));
typedef unsigned int uint_l __attribute__((address_space(3)));

// async 16B/lane global->LDS; lds dest wave-uniform (HW adds lane*16)
__device__ __forceinline__ void async_cp16(const void* g, void* l) {
    __builtin_amdgcn_global_load_lds((const uint_g*)g, (uint_l*)l, 16, 0, 0);
}

__device__ inline unsigned short f2bf(float f) {
    unsigned int u = __builtin_bit_cast(unsigned int, f);
    unsigned int r = (u + 0x7fffu + ((u >> 16) & 1u)) >> 16;   // RNE
    return (unsigned short)r;
}
__device__ inline float bf2f(unsigned short s) {
    unsigned int u = ((unsigned int)s) << 16;
    return __builtin_bit_cast(float, u);
}

// ---------------- Kernel P: convert K/V to bf16 in MFMA-B layout ----------------
__global__ __launch_bounds__(256) void prep_weights(
    const float* __restrict__ keys, const float* __restrict__ values,
    unsigned short* __restrict__ Kb, unsigned short* __restrict__ Vb)
{
    int idx = blockIdx.x * 256 + threadIdx.x;
    unsigned short o[8];
    if (idx < NEXP * 128 * 128) {            // keys: (e, k0 [128], n [128])
        int n = idx & 127, k0 = (idx >> 7) & 127, e = idx >> 14;
        const float* s = keys + ((size_t)e * DDIM + k0 * 8) * HDIM + n;
        #pragma unroll
        for (int j = 0; j < 8; ++j) o[j] = f2bf(s[(size_t)j * HDIM]);
        *(uint4*)&Kb[(size_t)idx * 8] = *(uint4*)o;
    } else {
        idx -= NEXP * 128 * 128;             // values: (e, k0 [16], n [1024])
        int n = idx & 1023, k0 = (idx >> 10) & 15, e = idx >> 14;
        const float* s = values + ((size_t)e * HDIM + k0 * 8) * DDIM + n;
        #pragma unroll
        for (int j = 0; j < 8; ++j) o[j] = f2bf(s[(size_t)j * DDIM]);
        *(uint4*)&Vb[(size_t)idx * 8] = *(uint4*)o;
    }
}

// ---------------- Kernel G1: gating partial logits (fp32, deterministic) ----------------
// grid (512 token-tiles, 4 d-chunks); block = 16 tok x 32 exp over 256 d
__global__ __launch_bounds__(256) void gate_partial(
    const float* __restrict__ x, const float* __restrict__ es,
    float* __restrict__ gpart)               // [4][NTOK][32]
{
    const int n0    = blockIdx.x * 16;
    const int dbase = blockIdx.y * 256;
    const int tid   = threadIdx.x;

    // union: staging tiles (4608 fp32) reused as partial buffer (4224 fp32)
    __shared__ float smem[4608];             // 18.4 KB -> 8 blocks/CU
    float* Xt  = smem;                       // [d][tok] stride 36
    float* Est = smem + 64 * 36;             // [d][e]   stride 36

    const int t4  = (tid & 3) * 4;           // 4 tokens
    const int e4  = ((tid >> 2) & 7) * 4;    // 4 experts
    const int rep = tid >> 5;                // d-replica 0..7

    const int xr = tid & 15, xc4 = (tid >> 4) * 4;   // X staging
    const int er = tid & 31, ec8 = (tid >> 5) * 8;   // es staging

    float acc[4][4] = {};

    for (int dc = dbase; dc < dbase + 256; dc += 64) {
        __syncthreads();
        {
            float4 v = *(const float4*)&x[(size_t)(n0 + xr) * DDIM + dc + xc4];
            Xt[(xc4 + 0) * 36 + xr] = v.x; Xt[(xc4 + 1) * 36 + xr] = v.y;
            Xt[(xc4 + 2) * 36 + xr] = v.z; Xt[(xc4 + 3) * 36 + xr] = v.w;
        }
        #pragma unroll
        for (int i = 0; i < 2; ++i) {
            float4 v = *(const float4*)&es[(size_t)er * DDIM + dc + ec8 + i * 4];
            Est[(ec8 + i * 4 + 0) * 36 + er] = v.x;
            Est[(ec8 + i * 4 + 1) * 36 + er] = v.y;
            Est[(ec8 + i * 4 + 2) * 36 + er] = v.z;
            Est[(ec8 + i * 4 + 3) * 36 + er] = v.w;
        }
        __syncthreads();

        #pragma unroll
        for (int s = 0; s < 8; ++s) {
            int d = s * 8 + rep;
            float4 xv = *(const float4*)&Xt[d * 36 + t4];
            float4 ev = *(const float4*)&Est[d * 36 + e4];
            const float xa[4] = {xv.x, xv.y, xv.z, xv.w};
            const float ea[4] = {ev.x, ev.y, ev.z, ev.w};
            #pragma unroll
            for (int i = 0; i < 4; ++i)
                #pragma unroll
                for (int j = 0; j < 4; ++j)
                    acc[i][j] = fmaf(xa[i], ea[j], acc[i][j]);
        }
    }

    __syncthreads();                          // staging tiles dead -> reuse as Lp
    float* Lp = smem;                         // [rep 8][tok 16][e 33]
    #pragma unroll
    for (int i = 0; i < 4; ++i)
        #pragma unroll
        for (int j = 0; j < 4; ++j)
            Lp[(rep * 16 + t4 + i) * 33 + e4 + j] = acc[i][j];
    __syncthreads();

    for (int p = tid; p < 16 * 32; p += 256) {
        int tok = p >> 5, e = p & 31;
        float s = 0.f;
        #pragma unroll
        for (int r = 0; r < 8; ++r) s += Lp[(r * 16 + tok) * 33 + e];
        gpart[((size_t)blockIdx.y * NTOK + n0 + tok) * NEXP + e] = s;
    }
}

// ---------------- Kernel G2: sum partials, top-4 (registers), scatter ----------------
// 32 blocks x 256 threads, one token per thread; LDS-aggregated atomics
__global__ __launch_bounds__(256) void topk_scatter(
    const float* __restrict__ gpart,         // [4][NTOK][32]
    int* __restrict__ cnt, int* __restrict__ tok_list, float* __restrict__ gates)
{
    const int tid = threadIdx.x;
    const int n   = blockIdx.x * 256 + tid;

    __shared__ int hist[NEXP];
    __shared__ int bbase[NEXP];
    if (tid < NEXP) hist[tid] = 0;

    // sum 4 partial chunks in fixed order; lg fully unrolled -> registers
    float lg[NEXP];
    #pragma unroll
    for (int i = 0; i < 8; ++i) {
        float4 v = *(const float4*)&gpart[(size_t)n * NEXP + i * 4];
        lg[i*4+0] = v.x; lg[i*4+1] = v.y; lg[i*4+2] = v.z; lg[i*4+3] = v.w;
    }
    #pragma unroll
    for (int j = 1; j < 4; ++j)
        #pragma unroll
        for (int i = 0; i < 8; ++i) {
            float4 v = *(const float4*)&gpart[((size_t)j * NTOK + n) * NEXP + i * 4];
            lg[i*4+0] += v.x; lg[i*4+1] += v.y; lg[i*4+2] += v.z; lg[i*4+3] += v.w;
        }

    // top-4, no dynamic array writes: mask previously-selected via constant-idx compares
    int sel[TOPK]; float sv[TOPK];
    #pragma unroll
    for (int j = 0; j < TOPK; ++j) {
        float bv = -3.0e38f; int bi = 0;
        #pragma unroll
        for (int e = 0; e < NEXP; ++e) {
            bool taken = false;
            #pragma unroll
            for (int q = 0; q < j; ++q) taken = taken || (sel[q] == e);
            float v = taken ? -3.0e38f : lg[e];
            if (v > bv) { bv = v; bi = e; }   // strict >: lowest idx wins ties
        }
        sel[j] = bi; sv[j] = bv;
    }

    __syncthreads();                          // hist init visible
    int lpos[TOPK];
    #pragma unroll
    for (int j = 0; j < TOPK; ++j) {
        gates[n * TOPK + j] = 1.f / (1.f + expf(-sv[j]));
        lpos[j] = atomicAdd(&hist[sel[j]], 1);      // LDS atomic
    }
    __syncthreads();
    if (tid < NEXP) bbase[tid] = atomicAdd(&cnt[tid], hist[tid]);  // 32 global atomics
    __syncthreads();
    #pragma unroll
    for (int j = 0; j < TOPK; ++j)
        tok_list[(size_t)sel[j] * NTOK + bbase[sel[j]] + lpos[j]] = n * TOPK + j;
}

// ---------------- Kernel F1: Hb[slot] = relu(X_tile @ K_e) * gate (bf16) ----------------
// grid (64 tiles, 32 experts); 32 tokens x 128 H, BK=64
__global__ __launch_bounds__(256) void ffn_phase1(
    const float* __restrict__ x,
    const unsigned short* __restrict__ Kb,   // [E][128][128][8]
    const int* __restrict__ cnt, const int* __restrict__ tok_list,
    const float* __restrict__ gates,
    unsigned short* __restrict__ Hb)         // [N*4][128]
{
    const int e = blockIdx.y, tile = blockIdx.x;
    const int c = cnt[e], base = tile * 32;
    if (base >= c) return;
    const int nt   = min(32, c - base);
    const int tid  = threadIdx.x, wave = tid >> 6, lane = tid & 63;
    const int lm   = lane & 15, quad = lane >> 4;
    const int r2   = (wave >> 1) * 16, c2 = (wave & 1) * 64;

    __shared__ __align__(16) unsigned short Xs[32 * 72];  // 4.6 KB
    __shared__ __align__(16) unsigned short Ks[8192];     // 16 KB (async dest)
    __shared__ int slot[32];
    __shared__ int toks[32];
    __shared__ float gs[32];

    if (tid < 32) {
        if (tid < nt) {
            int v = tok_list[(size_t)e * NTOK + base + tid];
            slot[tid] = v; toks[tid] = v >> 2; gs[tid] = gates[v];
        } else { slot[tid] = -1; toks[tid] = -1; gs[tid] = 0.f; }
    }
    __syncthreads();

    const unsigned short* Ke = Kb + (size_t)e * 131072;
    const int xr = tid >> 3, xseg = (tid & 7) * 8;
    const int xtok = toks[xr];
    const float* xrow = x + (size_t)(xtok < 0 ? 0 : xtok) * DDIM;

    f32x4 acc[4];
    #pragma unroll
    for (int j = 0; j < 4; ++j) acc[j] = (f32x4){0.f, 0.f, 0.f, 0.f};

    for (int dc = 0; dc < DDIM; dc += 64) {
        __syncthreads();                     // prior frag reads done
        #pragma unroll
        for (int i = 0; i < 4; ++i) {        // K chunk 16KB: 4 async/wave
            int u = wave * 4 + i;
            async_cp16(Ke + (size_t)dc * 128 + u * 512 + lane * 8, Ks + u * 512);
        }
        {                                    // X chunk: gather row, cvt bf16 (16B/thread)
            float4 v0 = make_float4(0.f,0.f,0.f,0.f), v1 = v0;
            if (xtok >= 0) {
                v0 = *(const float4*)&xrow[dc + xseg];
                v1 = *(const float4*)&xrow[dc + xseg + 4];
            }
            unsigned short p[8] = { f2bf(v0.x), f2bf(v0.y), f2bf(v0.z), f2bf(v0.w),
                                    f2bf(v1.x), f2bf(v1.y), f2bf(v1.z), f2bf(v1.w) };
            *(uint4*)&Xs[xr * 72 + xseg] = *(uint4*)p;
        }
        __syncthreads();                     // drains vmcnt (async K) too

        #pragma unroll
        for (int ks = 0; ks < 2; ++ks) {
            bf16x8 a = *(const bf16x8*)&Xs[(r2 + lm) * 72 + ks * 32 + quad * 8];
            #pragma unroll
            for (int tj = 0; tj < 4; ++tj) {
                bf16x8 b = *(const bf16x8*)&Ks[((ks * 4 + quad) * 128 + c2 + tj * 16 + lm) * 8];
                acc[tj] = __builtin_amdgcn_mfma_f32_16x16x32_bf16(a, b, acc[tj], 0, 0, 0);
            }
        }
    }

    // epilogue: relu * gate -> bf16 -> Hb[slot][col]
    #pragma unroll
    for (int reg = 0; reg < 4; ++reg) {
        int m = r2 + quad * 4 + reg;
        int s = slot[m];
        if (s >= 0) {
            float g = gs[m];
            unsigned short* hp = Hb + (size_t)s * HDIM;
            #pragma unroll
            for (int tj = 0; tj < 4; ++tj)
                hp[c2 + tj * 16 + lm] = f2bf(fmaxf(acc[tj][reg], 0.f) * g);
        }
    }
}

// ---------------- Kernel F2: Ob[slot] = Hb[slot] @ V_e (bf16, no atomics) ----------------
// grid (32 tiles, 8 nc, 32 experts); 64 slots x 128 D-cols, K=128 one shot
__global__ __launch_bounds__(256) void ffn_phase2(
    const unsigned short* __restrict__ Hb,   // [N*4][128]
    const unsigned short* __restrict__ Vb,   // [E][16][1024][8]
    const int* __restrict__ cnt, const int* __restrict__ tok_list,
    unsigned short* __restrict__ Ob)         // [N*4][1024] bf16
{
    const int e = blockIdx.z, nc = blockIdx.y, tile = blockIdx.x;
    const int c = cnt[e], base = tile * 64;
    if (base >= c) return;
    const int nt   = min(64, c - base);
    const int tid  = threadIdx.x, wave = tid >> 6, lane = tid & 63;
    const int lm   = lane & 15, quad = lane >> 4;
    const int r2   = (wave >> 1) * 32, c2 = (wave & 1) * 64;

    __shared__ __align__(16) unsigned short Hs[64 * 136];  // 17.4 KB
    __shared__ __align__(16) unsigned short Vs[16384];     // 32 KB (async dest)
    __shared__ int slot[64];

    if (tid < 64) {
        if (tid < nt) slot[tid] = tok_list[(size_t)e * NTOK + base + tid];
        else          slot[tid] = -1;
    }
    __syncthreads();

    const unsigned short* Ve = Vb + (size_t)e * 131072;
    #pragma unroll
    for (int i = 0; i < 8; ++i) {            // V chunk 32KB: 8 async/wave
        int u = wave * 8 + i;                // (k0, half)
        int k0 = u >> 1, half = u & 1;
        async_cp16(Ve + ((size_t)k0 * 1024 + nc * 128 + half * 64 + lane) * 8,
                   Vs + u * 512);
    }
    {                                        // H tile gather: 64 rows x 256B
        const int hr = tid >> 2, part = tid & 3;
        int s = slot[hr];
        uint4 z = {0u, 0u, 0u, 0u};
        uint4 d0 = z, d1 = z, d2 = z, d3 = z;
        if (s >= 0) {
            const uint4* src = (const uint4*)(Hb + (size_t)s * HDIM + part * 32);
            d0 = src[0]; d1 = src[1]; d2 = src[2]; d3 = src[3];
        }
        uint4* dst = (uint4*)&Hs[hr * 136 + part * 32];
        dst[0] = d0; dst[1] = d1; dst[2] = d2; dst[3] = d3;
    }
    __syncthreads();

    f32x4 acc[2][4];
    #pragma unroll
    for (int i = 0; i < 2; ++i)
        #pragma unroll
        for (int j = 0; j < 4; ++j) acc[i][j] = (f32x4){0.f, 0.f, 0.f, 0.f};

    #pragma unroll
    for (int ks = 0; ks < 4; ++ks) {
        bf16x8 a0 = *(const bf16x8*)&Hs[(r2 + lm) * 136 + ks * 32 + quad * 8];
        bf16x8 a1 = *(const bf16x8*)&Hs[(r2 + 16 + lm) * 136 + ks * 32 + quad * 8];
        #pragma unroll
        for (int tj = 0; tj < 4; ++tj) {
            bf16x8 b = *(const bf16x8*)&Vs[((ks * 4 + quad) * 128 + c2 + tj * 16 + lm) * 8];
            acc[0][tj] = __builtin_amdgcn_mfma_f32_16x16x32_bf16(a0, b, acc[0][tj], 0, 0, 0);
            acc[1][tj] = __builtin_amdgcn_mfma_f32_16x16x32_bf16(a1, b, acc[1][tj], 0, 0, 0);
        }
    }

    // epilogue: plain bf16 stores (slot rows are unique -> no atomics)
    #pragma unroll
    for (int ti = 0; ti < 2; ++ti)
        #pragma unroll
        for (int reg = 0; reg < 4; ++reg) {
            int m = r2 + ti * 16 + quad * 4 + reg;
            int s = slot[m];
            if (s >= 0) {
                unsigned short* op = Ob + (size_t)s * DDIM + nc * 128 + c2 + lm;
                #pragma unroll
                for (int tj = 0; tj < 4; ++tj)
                    op[tj * 16] = f2bf(acc[ti][tj][reg]);
            }
        }
}

// ---------------- Kernel R: out[n] = sum_j Ob[4n+j]  (bf16 -> fp32) ----------------
__global__ __launch_bounds__(256) void reduce_out(
    const unsigned short* __restrict__ Ob, float* __restrict__ out)
{
    const int tid = threadIdx.x;
    const int n   = blockIdx.x * 2 + (tid >> 7);
    const int cc  = (tid & 127) * 8;

    float s[8] = {};
    #pragma unroll
    for (int j = 0; j < 4; ++j) {
        uint4 v = *(const uint4*)&Ob[((size_t)n * 4 + j) * DDIM + cc];
        const unsigned int w[4] = {v.x, v.y, v.z, v.w};
        #pragma unroll
        for (int q = 0; q < 4; ++q) {
            s[q * 2 + 0] += bf2f((unsigned short)(w[q] & 0xffff));
            s[q * 2 + 1] += bf2f((unsigned short)(w[q] >> 16));
        }
    }
    float4 o0 = {s[0], s[1], s[2], s[3]};
    float4 o1 = {s[4], s[5], s[6], s[7]};
    *(float4*)&out[(size_t)n * DDIM + cc]     = o0;
    *(float4*)&out[(size_t)n * DDIM + cc + 4] = o1;
}

extern "C" void kernel_launch(void* const* d_in, const int* in_sizes, int n_in,
                              void* d_out, int out_size, void* d_ws, size_t ws_size,
                              hipStream_t stream) {
    const float* x      = (const float*)d_in[0];
    const float* es     = (const float*)d_in[1];
    const float* keys   = (const float*)d_in[2];
    const float* values = (const float*)d_in[3];
    float* out          = (float*)d_out;

    // workspace layout (~97 MB)
    char* w = (char*)d_ws;
    int*   cnt      = (int*)w;               w += 256;
    int*   tok_list = (int*)w;               w += (size_t)NEXP * NTOK * sizeof(int);    // 1 MB
    float* gates    = (float*)w;             w += (size_t)NTOK * TOPK * sizeof(float);  // 128 KB
    float* gpart    = (float*)w;             w += (size_t)4 * NTOK * NEXP * sizeof(float); // 4 MB
    unsigned short* Kb = (unsigned short*)w; w += (size_t)NEXP * 128 * 128 * 8 * 2;     // 8 MB
    unsigned short* Vb = (unsigned short*)w; w += (size_t)NEXP * 16 * 1024 * 8 * 2;     // 8 MB
    unsigned short* Hb = (unsigned short*)w; w += (size_t)NTOK * TOPK * HDIM * 2;       // 8.4 MB
    unsigned short* Ob = (unsigned short*)w;                                            // 67 MB

    hipMemsetAsync(cnt, 0, NEXP * sizeof(int), stream);

    prep_weights<<<4096, 256, 0, stream>>>(keys, values, Kb, Vb);
    gate_partial<<<dim3(NTOK / 16, 4), 256, 0, stream>>>(x, es, gpart);
    topk_scatter<<<NTOK / 256, 256, 0, stream>>>(gpart, cnt, tok_list, gates);

    ffn_phase1<<<dim3(64, NEXP), 256, 0, stream>>>(x, Kb, cnt, tok_list, gates, Hb);
    ffn_phase2<<<dim3(32, 8, NEXP), 256, 0, stream>>>(Hb, Vb, cnt, tok_list, Ob);
    reduce_out<<<NTOK / 2, 256, 0, stream>>>(Ob, out);
}